// Round 9
// baseline (1390.830 us; speedup 1.0000x reference)
//
#include <hip/hip_runtime.h>
#include <stdint.h>

typedef __bf16  bf16x8 __attribute__((ext_vector_type(8)));
typedef float   f32x4  __attribute__((ext_vector_type(4)));
typedef short   s16x2  __attribute__((ext_vector_type(2)));
typedef unsigned short u16;

#define TEMP 5.0f

// ---------- helpers ----------
__device__ inline float wsum(float v){
  #pragma unroll
  for (int off=32; off; off>>=1) v += __shfl_xor(v, off, 64);
  return v;
}
__device__ inline float wmax(float v){
  #pragma unroll
  for (int off=32; off; off>>=1) v = fmaxf(v, __shfl_xor(v, off, 64));
  return v;
}
__device__ inline u16 f2bf(float f){               // RNE float->bf16
  unsigned u = __float_as_uint(f);
  u = u + 0x7fffu + ((u>>16)&1u);
  return (u16)(u>>16);
}
__device__ inline float bfl(unsigned u){ return __uint_as_float(u<<16); }
__device__ inline float bfh(unsigned u){ return __uint_as_float(u & 0xffff0000u); }

__device__ inline s16x2 as_s16x2(int v){ union{int i; s16x2 v;} u; u.i=v; return u.v; }

__device__ inline s16x2 pkmin2(s16x2 a, s16x2 b){
  s16x2 r; r.x = a.x < b.x ? a.x : b.x; r.y = a.y < b.y ? a.y : b.y; return r;
}
__device__ inline s16x2 pkmax2(s16x2 a, s16x2 b){
  s16x2 r; r.x = a.x > b.x ? a.x : b.x; r.y = a.y > b.y ? a.y : b.y; return r;
}

// ---- 8-lane subgroup reduce over lane bits {0,1,4}: DPP quad_perm xor1/xor2
// (pure VALU) + permlane16_swap (^16, pure VALU). No LDS round-trips.
#if __has_builtin(__builtin_amdgcn_mov_dpp)
__device__ inline int dxor1(int v){ return __builtin_amdgcn_mov_dpp(v, 0xB1, 0xF, 0xF, true); } // quad_perm [1,0,3,2]
__device__ inline int dxor2(int v){ return __builtin_amdgcn_mov_dpp(v, 0x4E, 0xF, 0xF, true); } // quad_perm [2,3,0,1]
#else
__device__ inline int dxor1(int v){ return __shfl_xor(v, 1, 64); }
__device__ inline int dxor2(int v){ return __shfl_xor(v, 2, 64); }
#endif

#if __has_builtin(__builtin_amdgcn_permlane16_swap)
__device__ inline int x16sum_i(int c){
  auto p = __builtin_amdgcn_permlane16_swap((unsigned)c, (unsigned)c, false, false);
  return (int)p[0] + (int)p[1];
}
__device__ inline int x16min_i(int c){
  auto p = __builtin_amdgcn_permlane16_swap((unsigned)c, (unsigned)c, false, false);
  return min((int)p[0], (int)p[1]);
}
__device__ inline int x16max_i(int c){
  auto p = __builtin_amdgcn_permlane16_swap((unsigned)c, (unsigned)c, false, false);
  return max((int)p[0], (int)p[1]);
}
__device__ inline float x16sum_f(float v){
  auto p = __builtin_amdgcn_permlane16_swap(__float_as_uint(v), __float_as_uint(v), false, false);
  return __uint_as_float(p[0]) + __uint_as_float(p[1]);
}
#else
__device__ inline int   x16sum_i(int c){ return c + __shfl_xor(c, 16, 64); }
__device__ inline int   x16min_i(int c){ return min(c, __shfl_xor(c, 16, 64)); }
__device__ inline int   x16max_i(int c){ return max(c, __shfl_xor(c, 16, 64)); }
__device__ inline float x16sum_f(float v){ return v + __shfl_xor(v, 16, 64); }
#endif

__device__ inline int ssum8_i(int c){ c += dxor1(c); c += dxor2(c); return x16sum_i(c); }
__device__ inline int smin8_i(int c){ c = min(c, dxor1(c)); c = min(c, dxor2(c)); return x16min_i(c); }
__device__ inline int smax8_i(int c){ c = max(c, dxor1(c)); c = max(c, dxor2(c)); return x16max_i(c); }
__device__ inline float ssum8_f(float v){
  v += __int_as_float(dxor1(__float_as_int(v)));
  v += __int_as_float(dxor2(__float_as_int(v)));
  return x16sum_f(v);
}

// ---------- K0: normalize image features (32x512) ----------
__global__ void k_img(const float* __restrict__ X, float* __restrict__ imgn){
  int b = blockIdx.x, lane = threadIdx.x;
  const float* src = X + (size_t)b*512 + lane*8;
  float4 a = *(const float4*)src;
  float4 c = *(const float4*)(src+4);
  float ss = a.x*a.x+a.y*a.y+a.z*a.z+a.w*a.w + c.x*c.x+c.y*c.y+c.z*c.z+c.w*c.w;
  ss = wsum(ss);
  float inv = 1.0f/sqrtf(ss);
  float* dst = imgn + (size_t)b*512 + lane*8;
  float4 o0 = {a.x*inv,a.y*inv,a.z*inv,a.w*inv};
  float4 o1 = {c.x*inv,c.y*inv,c.z*inv,c.w*inv};
  *(float4*)dst = o0; *(float4*)(dst+4) = o1;
}

// ---------- K1: normalize txt; bf16 K-chunked TXT[kc][cn(51008)][32]; invn[n*1000+c] ----------
__global__ void k_txt(const float* __restrict__ X, u16* __restrict__ TXT, float* __restrict__ invn){
  int cn = blockIdx.x, lane = threadIdx.x;
  int kc = lane>>2, kk8 = (lane&3)*8;
  size_t dstE = ((size_t)kc*51008 + cn)*32 + kk8;
  if (cn >= 51000){
    uint4 z = {0,0,0,0};
    *(uint4*)(TXT + dstE) = z;
    return;
  }
  int c = cn/51, n = cn - c*51;
  const float* src = X + ((size_t)n*1000 + c)*512 + lane*8;
  float4 a = *(const float4*)src;
  float4 d = *(const float4*)(src+4);
  float ss = a.x*a.x+a.y*a.y+a.z*a.z+a.w*a.w + d.x*d.x+d.y*d.y+d.z*d.z+d.w*d.w;
  ss = wsum(ss);
  float inv = 1.0f/sqrtf(ss);
  u16 h0=f2bf(a.x*inv),h1=f2bf(a.y*inv),h2=f2bf(a.z*inv),h3=f2bf(a.w*inv);
  u16 h4=f2bf(d.x*inv),h5=f2bf(d.y*inv),h6=f2bf(d.z*inv),h7=f2bf(d.w*inv);
  uint4 o;
  o.x = (unsigned)h0 | ((unsigned)h1<<16);
  o.y = (unsigned)h2 | ((unsigned)h3<<16);
  o.z = (unsigned)h4 | ((unsigned)h5<<16);
  o.w = (unsigned)h6 | ((unsigned)h7<<16);
  *(uint4*)(TXT + dstE) = o;
  if (lane==0) invn[(size_t)n*1000 + c] = inv;
}

// ---------- K2: mean_txt[c] = l2norm( sum_n txt_n[c] ) ----------
__global__ void k_mean(const float* __restrict__ X, const float* __restrict__ invn, float* __restrict__ MT){
  int c = blockIdx.x, tid = threadIdx.x, lane = tid&63, wv = tid>>6;
  __shared__ float sinv[51];
  __shared__ float red[4];
  if (tid < 51) sinv[tid] = invn[(size_t)tid*1000 + c];
  __syncthreads();
  int d0 = tid*2;
  float sx=0.f, sy=0.f;
  for (int n=0;n<51;++n){
    const float2 x = *(const float2*)(X + ((size_t)n*1000 + c)*512 + d0);
    float iv = sinv[n];
    sx += x.x*iv; sy += x.y*iv;
  }
  float ss = sx*sx + sy*sy;
  ss = wsum(ss);
  if (lane==0) red[wv] = ss;
  __syncthreads();
  float tot = red[0]+red[1]+red[2]+red[3];
  float inv = 1.0f/sqrtf(tot);
  float2 o = {sx*inv, sy*inv};
  *(float2*)(MT + (size_t)c*512 + d0) = o;
}

// ---------- K3: v[c,n] = softmax_n( TEMP * mean_txt[c].txt[n,c] ) ----------
__global__ void k_v(const u16* __restrict__ TXT, const float* __restrict__ MT, float* __restrict__ vbuf){
  int c = blockIdx.x, lane = threadIdx.x;
  __shared__ float lg[51];
  const float* mp = MT + (size_t)c*512 + lane*8;
  float4 m0 = *(const float4*)mp;
  float4 m1 = *(const float4*)(mp+4);
  int kc = lane>>2, kk8 = (lane&3)*8;
  for (int n=0;n<51;++n){
    size_t e = ((size_t)kc*51008 + (size_t)(c*51+n))*32 + kk8;
    uint4 q = *(const uint4*)(TXT + e);
    float d = bfl(q.x)*m0.x + bfh(q.x)*m0.y + bfl(q.y)*m0.z + bfh(q.y)*m0.w
            + bfl(q.z)*m1.x + bfh(q.z)*m1.y + bfl(q.w)*m1.z + bfh(q.w)*m1.w;
    d = wsum(d);
    if (lane==0) lg[n] = d;
  }
  __syncthreads();
  float val = (lane<51) ? lg[lane] : -1e30f;
  float mx = wmax(val);
  float e = (lane<51) ? expf(TEMP*(val-mx)) : 0.f;
  float s = wsum(e);
  if (lane<51) vbuf[(size_t)c*51 + lane] = e/s;
}

// ---------- K4: bias[b,c] = base_logits ----------
__global__ void k_base(const float* __restrict__ imgn, const float* __restrict__ MT, float* __restrict__ bias){
  int c = blockIdx.x, lane = threadIdx.x;
  const float* mp = MT + (size_t)c*512 + lane*8;
  float4 m0 = *(const float4*)mp;
  float4 m1 = *(const float4*)(mp+4);
  for (int b=0;b<32;++b){
    const float* ip = imgn + (size_t)b*512 + lane*8;
    float4 i0 = *(const float4*)ip;
    float4 i1 = *(const float4*)(ip+4);
    float d = i0.x*m0.x+i0.y*m0.y+i0.z*m0.z+i0.w*m0.w
            + i1.x*m1.x+i1.y*m1.y+i1.z*m1.z+i1.w*m1.w;
    d = wsum(d);
    if (lane==0) bias[(size_t)b*1000 + c] = d;
  }
}

// ---------- K5: normalize loc; LOC[b][kc][m(224)][32] bf16; ew[b,m] (0 for m>=196) ----------
__global__ void k_loc(const float* __restrict__ L, const float* __restrict__ imgn,
                      u16* __restrict__ LOC, float* __restrict__ ewg){
  int m = blockIdx.x, b = blockIdx.y, lane = threadIdx.x;
  size_t dstE = ((size_t)(b*16 + (lane>>2))*224 + m)*32 + (lane&3)*8;
  if (m >= 196){
    uint4 z = {0,0,0,0};
    *(uint4*)(LOC + dstE) = z;
    if (lane==0) ewg[(size_t)b*224 + m] = 0.f;
    return;
  }
  const float* src = L + ((size_t)b*196 + m)*512 + lane*8;
  float4 a = *(const float4*)src;
  float4 d = *(const float4*)(src+4);
  const float* ip = imgn + (size_t)b*512 + lane*8;
  float4 i0 = *(const float4*)ip;
  float4 i1 = *(const float4*)(ip+4);
  float ss = a.x*a.x+a.y*a.y+a.z*a.z+a.w*a.w + d.x*d.x+d.y*d.y+d.z*d.z+d.w*d.w;
  float ws = a.x*i0.x+a.y*i0.y+a.z*i0.z+a.w*i0.w + d.x*i1.x+d.y*i1.y+d.z*i1.z+d.w*i1.w;
  ss = wsum(ss); ws = wsum(ws);
  float inv = 1.0f/sqrtf(ss);
  u16 h0=f2bf(a.x*inv),h1=f2bf(a.y*inv),h2=f2bf(a.z*inv),h3=f2bf(a.w*inv);
  u16 h4=f2bf(d.x*inv),h5=f2bf(d.y*inv),h6=f2bf(d.z*inv),h7=f2bf(d.w*inv);
  uint4 o;
  o.x = (unsigned)h0 | ((unsigned)h1<<16);
  o.y = (unsigned)h2 | ((unsigned)h3<<16);
  o.z = (unsigned)h4 | ((unsigned)h5<<16);
  o.w = (unsigned)h6 | ((unsigned)h7<<16);
  *(uint4*)(LOC + dstE) = o;
  if (lane==0) ewg[(size_t)b*224 + m] = expf(TEMP * ws * inv);
}

// ---------- K6: fused GEMM (MFMA bf16) + in-register top-50 + weighted sum ----------
// THIS ROUND: barrier-free K-loop, A direct-to-register. R8 post-mortem: M-major
// tiling made every A-fragment single-consumer (per col-half), so the whole
// global->LDS->reg round trip for A (cp16 issue, vmcnt(0) drain at each of 16
// __syncthreads, ds_read, dbuf) serves a sharing pattern that no longer exists;
// issue is saturated (VALU 64 + MFMA 20 ~ 84%) and the barrier drain gangs all
// 8 waves 16x/block. Fix: per kc each wave global-loads its own NT A-fragments
// (64 lanes x 16B = 1KB contiguous, perfectly coalesced, L2-hot) + 2 B-frags,
// then MFMAs. ZERO LDS and ZERO barriers in the K-loop -> waves desynchronize,
// VMEM latency hidden by 8 waves/SIMD instead of ganged. VMEM volume unchanged
// (cp16 was VMEM too); A-swizzle pair cancels (direct read needs none).
// LDS now epilogue-only (exchange 29696B + ewl 896B). Liveness: acc32 + af<=16
// + B8 + addr ~8 <= 64-reg budget at (512,8).
// Epilogue unchanged from R8: keys m-ordered in 4 slabs x [16 cols][116 u32];
// wave (wv>>1, wv&1) selects 8 cols x 8 lanes x 28 keys; sentinel pads at
// sub==7; integer Illinois false-position (exact c==50 / width<=1 exits);
// DPP+permlane 8-lane reduces; 16-bit keys k=(int)(x*15360).
// acc[]/kk[] compile-time indices only (scratch-demotion trap).
__global__ __launch_bounds__(512,8) void k_main(const u16* __restrict__ TXT, const u16* __restrict__ LOC,
                                                const float* __restrict__ ewg, const float* __restrict__ vbuf,
                                                float* __restrict__ bias){
  __shared__ __align__(16) char smem[30592];   // key-exchange 4x7424B=29696 | ewl @29696 (896B)
  const int tid = threadIdx.x, lane = tid & 63, wv = tid >> 6;   // 8 waves
  const int quad = lane >> 4, l16 = lane & 15;
  const int wm = wv >> 1, wn = wv & 1;         // wm: m-quarter (4 tiles; wm=3: 2), wn: 32-col half
  const int sub = (lane & 3) | ((lane >> 2) & 4);        // selection: lane bits {0,1,4}
  const int col = ((lane >> 2) & 3) | ((lane >> 3) & 4); // selection: lane bits {2,3,5}

  // group swizzle: groups of 32 cn-tiles x 32 b; last group 29 x 32
  int id = blockIdx.x, b, cnt_;
  if (id < 24576){
    int g = id >> 10, r = id & 1023;
    b = r >> 5;  cnt_ = (g << 5) + (r & 31);
  } else {
    int r = id - 24576;
    b = r / 29;  cnt_ = 768 + r % 29;
  }
  const int cn0 = cnt_ * 64;

  // stage ew early (read only after the pre-exchange barrier)
  float* ewl = (float*)(smem + 29696);
  if (tid < 224) ewl[tid] = ewg[(size_t)b*224 + tid];

  const f32x4 zero = {0.f,0.f,0.f,0.f};
  f32x4 acc[4][2];
  #pragma unroll
  for (int t=0;t<4;++t){ acc[t][0]=zero; acc[t][1]=zero; }

  // per-wave direct global A/B bases
  // A: LOC[b][kc][m][32]: row m = 64*wm + 16*t + l16, 16B slot quad
  const u16* Aw = LOC + (size_t)(b*16)*7168 + (size_t)((64*wm + l16))*32 + quad*8;
  // B: TXT[kc][cn][32]: cn = cn0 + 32*wn + l16 (x), +16 (y)
  const u16* Bw = TXT + (size_t)(cn0 + 32*wn + l16)*32 + quad*8;

  if (wm != 3){
    for (int kc = 0; kc < 16; ++kc){
      const u16* ak = Aw + (size_t)kc*7168;
      const u16* bk = Bw + (size_t)kc*(51008*32);
      bf16x8 bx  = *(const bf16x8*)(bk);
      bf16x8 by  = *(const bf16x8*)(bk + 512);
      bf16x8 af0 = *(const bf16x8*)(ak);
      bf16x8 af1 = *(const bf16x8*)(ak + 512);
      bf16x8 af2 = *(const bf16x8*)(ak + 1024);
      bf16x8 af3 = *(const bf16x8*)(ak + 1536);
      acc[0][0] = __builtin_amdgcn_mfma_f32_16x16x32_bf16(af0, bx, acc[0][0], 0,0,0);
      acc[0][1] = __builtin_amdgcn_mfma_f32_16x16x32_bf16(af0, by, acc[0][1], 0,0,0);
      acc[1][0] = __builtin_amdgcn_mfma_f32_16x16x32_bf16(af1, bx, acc[1][0], 0,0,0);
      acc[1][1] = __builtin_amdgcn_mfma_f32_16x16x32_bf16(af1, by, acc[1][1], 0,0,0);
      acc[2][0] = __builtin_amdgcn_mfma_f32_16x16x32_bf16(af2, bx, acc[2][0], 0,0,0);
      acc[2][1] = __builtin_amdgcn_mfma_f32_16x16x32_bf16(af2, by, acc[2][1], 0,0,0);
      acc[3][0] = __builtin_amdgcn_mfma_f32_16x16x32_bf16(af3, bx, acc[3][0], 0,0,0);
      acc[3][1] = __builtin_amdgcn_mfma_f32_16x16x32_bf16(af3, by, acc[3][1], 0,0,0);
    }
  } else {
    for (int kc = 0; kc < 16; ++kc){
      const u16* ak = Aw + (size_t)kc*7168;
      const u16* bk = Bw + (size_t)kc*(51008*32);
      bf16x8 bx  = *(const bf16x8*)(bk);
      bf16x8 by  = *(const bf16x8*)(bk + 512);
      bf16x8 af0 = *(const bf16x8*)(ak);
      bf16x8 af1 = *(const bf16x8*)(ak + 512);
      acc[0][0] = __builtin_amdgcn_mfma_f32_16x16x32_bf16(af0, bx, acc[0][0], 0,0,0);
      acc[0][1] = __builtin_amdgcn_mfma_f32_16x16x32_bf16(af0, by, acc[0][1], 0,0,0);
      acc[1][0] = __builtin_amdgcn_mfma_f32_16x16x32_bf16(af1, bx, acc[1][0], 0,0,0);
      acc[1][1] = __builtin_amdgcn_mfma_f32_16x16x32_bf16(af1, by, acc[1][1], 0,0,0);
    }
  }

  // ---- epilogue: pack keys to LDS in m-order, re-read split by columns ----
  // slab s = 2wn+n in [0,4): [16 cols][116 u32]; u32 idx within col = m/2.
  const int NT = (wm == 3) ? 2 : 4;
  const float KSC = 15360.0f;
  {
    #pragma unroll
    for (int n=0;n<2;++n){
      unsigned* wr = (unsigned*)(void*)smem + (size_t)((2*wn + n)*1856) + l16*116 + quad*2;
      #pragma unroll
      for (int t=0;t<4;++t){
        if (t < NT){
          int a0 = (int)(acc[t][n][0]*KSC), a1 = (int)(acc[t][n][1]*KSC);
          int a2 = (int)(acc[t][n][2]*KSC), a3 = (int)(acc[t][n][3]*KSC);
          uint2 o; o.x = (unsigned)((a0 & 0xffff) | (a1<<16)); o.y = (unsigned)((a2 & 0xffff) | (a3<<16));
          *(uint2*)(wr + (4*wm + t)*8) = o;
        }
      }
    }
  }
  __syncthreads();

  int kk[7][2];
  {
    const unsigned* rd = (const unsigned*)(void*)smem + (size_t)((wv>>1)*1856) + ((wv&1)*8 + col)*116 + sub*14;
    #pragma unroll
    for (int j=0;j<7;++j){
      uint2 q = *(const uint2*)(rd + 2*j);
      kk[j][0] = (int)q.x;
      kk[j][1] = (int)q.y;
    }
  }
  // pads: m>=196 <=> u32 idx>=98 <=> sub==7 (idx = sub*14 + [0,14)) -> whole lane
  const int PKPK = (int)0xC180C180;  // two packed -16000 sentinels (below all real keys)
  if (sub == 7){
    #pragma unroll
    for (int j=0;j<7;++j){ kk[j][0] = PKPK; kk[j][1] = PKPK; }
  }

  // ---- bracket (sub<7 lanes cover exactly m=0..195, all real) ----
  s16x2 vmn = as_s16x2(kk[0][0]), vmx = vmn;
  #pragma unroll
  for (int j=0;j<7;++j){
    #pragma unroll
    for (int i=0;i<2;++i){
      vmn = pkmin2(vmn, as_s16x2(kk[j][i]));
      vmx = pkmax2(vmx, as_s16x2(kk[j][i]));
    }
  }
  int kmn = min((int)vmn.x, (int)vmn.y);
  int kmx = max((int)vmx.x, (int)vmx.y);
  if (sub == 7){ kmn = 32000; kmx = -32000; }   // exclude sentinel lane from bracket
  kmn = smin8_i(kmn);
  kmx = smax8_i(kmx);
  int lo = kmn - 1, hi = kmx + 1;   // cnt(lo)=196>=50, cnt(hi)=0<50; tm>lo>-16000 -> pads never counted

  // ---- integer false position (Illinois) on packed counts ----
  float flo = 146.0f, fhi = -50.0f;   // counts-50 at lo/hi
  int side = 0;
  bool done = false;

  #pragma unroll 1
  for (int it = 0; it < 14; ++it){
    float fr = flo * __builtin_amdgcn_rcpf(flo - fhi);
    fr = fminf(fmaxf(fr, 0.04f), 0.96f);
    int tm = lo + (int)(fr * (float)(hi - lo));
    tm = (tm <= lo) ? (lo + 1) : ((tm >= hi) ? (hi - 1) : tm);

    s16x2 tmv = as_s16x2((tm & 0xffff) | (tm << 16));
    s16x2 ca = {0,0};
    #pragma unroll
    for (int j=0;j<7;++j){
      ca = ca + ((as_s16x2(kk[j][0]) - tmv) >> 15);
      ca = ca + ((as_s16x2(kk[j][1]) - tmv) >> 15);
    }
    int clt = -((int)ca.x + (int)ca.y);    // lane's below-count (of 28; sentinels below)
    int c = ssum8_i(28 - clt);             // column's >=tm count (real only)

    bool ge = (c >= 50);
    if (!done){
      if (ge){ fhi = (side==1)  ? fhi*0.5f : fhi; flo = (float)(c-50); lo = tm; side = 1; }
      else   { flo = (side==-1) ? flo*0.5f : flo; fhi = (float)(c-50); hi = tm; side = -1; }
    }
    done = done || (c == 50) || ((hi - lo) <= 1);
    if (__all(done)) break;
  }
  const int thr = lo;

  // ---- final weighted sum: x = key/15360; ew via m = 28*sub + 4j + {0..3} ----
  float num = 0.f, den = 0.f;
  #pragma unroll
  for (int j=0;j<7;++j){
    float2 e0 = *(const float2*)(ewl + 28*sub + 4*j);
    float2 e1 = *(const float2*)(ewl + 28*sub + 4*j + 2);
    int a0 = (kk[j][0]<<16)>>16, a1 = kk[j][0]>>16;
    int a2 = (kk[j][1]<<16)>>16, a3 = kk[j][1]>>16;
    if (a0 >= thr){ num = fmaf((float)a0, e0.x, num); den += e0.x; }
    if (a1 >= thr){ num = fmaf((float)a1, e0.y, num); den += e0.y; }
    if (a2 >= thr){ num = fmaf((float)a2, e1.x, num); den += e1.x; }
    if (a3 >= thr){ num = fmaf((float)a3, e1.y, num); den += e1.y; }
  }
  num = ssum8_f(num);
  den = ssum8_f(den);

  int cn = cn0 + (wv>>1)*16 + (wv&1)*8 + col;
  if (sub == 0 && cn < 51000){
    int c = cn/51;
    atomicAdd(bias + (size_t)b*1000 + c, vbuf[cn]*(num/(den*KSC)));
  }
}

// ---------- K7: out = fp32( exp(logit_scale) * bias ) ----------
__global__ void k_out(const float* __restrict__ bias, const float* __restrict__ ls, float* __restrict__ out){
  int i = blockIdx.x*256 + threadIdx.x;
  if (i < 32000){
    float sc = expf(ls[0]);
    out[i] = sc * bias[i];
  }
}

// ---------- launch ----------
extern "C" void kernel_launch(void* const* d_in, const int* in_sizes, int n_in,
                              void* d_out, int out_size, void* d_ws, size_t ws_size,
                              hipStream_t stream) {
  const float* img = (const float*)d_in[0];
  const float* loc = (const float*)d_in[1];
  const float* txt = (const float*)d_in[2];
  const float* ls  = (const float*)d_in[3];
  char* ws = (char*)d_ws;
  float* imgn = (float*)(ws + 0);            //  65536
  float* MT   = (float*)(ws + 65536);        //  2048000
  float* invn = (float*)(ws + 2113536);      //  204032
  float* vbuf = (float*)(ws + 2317568);      //  204032
  float* ewg  = (float*)(ws + 2521600);      //  28672
  float* bias = (float*)(ws + 2550272);      //  128000
  u16*   TXT  = (u16*)  (ws + 2678272);      //  52232192
  u16*   LOC  = (u16*)  (ws + 54910464);     //  7340032

  k_img <<<dim3(32),      dim3(64),  0, stream>>>(img, imgn);
  k_txt <<<dim3(51008),   dim3(64),  0, stream>>>(txt, TXT, invn);
  k_mean<<<dim3(1000),    dim3(256), 0, stream>>>(txt, invn, MT);
  k_v   <<<dim3(1000),    dim3(64),  0, stream>>>(TXT, MT, vbuf);
  k_base<<<dim3(1000),    dim3(64),  0, stream>>>(imgn, MT, bias);
  k_loc <<<dim3(224,32),  dim3(64),  0, stream>>>(loc, imgn, LOC, ewg);
  k_main<<<dim3(25504),   dim3(512), 0, stream>>>(TXT, LOC, ewg, vbuf, bias);
  k_out <<<dim3(125),     dim3(256), 0, stream>>>(bias, ls, (float*)d_out);
}

// Round 10
// 1006.720 us; speedup vs baseline: 1.3815x; 1.3815x over previous
//
#include <hip/hip_runtime.h>
#include <stdint.h>

typedef __bf16  bf16x8 __attribute__((ext_vector_type(8)));
typedef float   f32x4  __attribute__((ext_vector_type(4)));
typedef short   s16x2  __attribute__((ext_vector_type(2)));
typedef unsigned short u16;

#define TEMP 5.0f

// ---------- helpers ----------
__device__ inline float wsum(float v){
  #pragma unroll
  for (int off=32; off; off>>=1) v += __shfl_xor(v, off, 64);
  return v;
}
__device__ inline float wmax(float v){
  #pragma unroll
  for (int off=32; off; off>>=1) v = fmaxf(v, __shfl_xor(v, off, 64));
  return v;
}
__device__ inline u16 f2bf(float f){               // RNE float->bf16
  unsigned u = __float_as_uint(f);
  u = u + 0x7fffu + ((u>>16)&1u);
  return (u16)(u>>16);
}
__device__ inline float bfl(unsigned u){ return __uint_as_float(u<<16); }
__device__ inline float bfh(unsigned u){ return __uint_as_float(u & 0xffff0000u); }

__device__ inline s16x2 as_s16x2(int v){ union{int i; s16x2 v;} u; u.i=v; return u.v; }

__device__ inline s16x2 pkmin2(s16x2 a, s16x2 b){
  s16x2 r; r.x = a.x < b.x ? a.x : b.x; r.y = a.y < b.y ? a.y : b.y; return r;
}
__device__ inline s16x2 pkmax2(s16x2 a, s16x2 b){
  s16x2 r; r.x = a.x > b.x ? a.x : b.x; r.y = a.y > b.y ? a.y : b.y; return r;
}

// ---- 8-lane subgroup reduce over lane bits {0,1,4}: DPP quad_perm xor1/xor2
// (pure VALU) + permlane16_swap (^16, pure VALU). No LDS round-trips.
#if __has_builtin(__builtin_amdgcn_mov_dpp)
__device__ inline int dxor1(int v){ return __builtin_amdgcn_mov_dpp(v, 0xB1, 0xF, 0xF, true); } // quad_perm [1,0,3,2]
__device__ inline int dxor2(int v){ return __builtin_amdgcn_mov_dpp(v, 0x4E, 0xF, 0xF, true); } // quad_perm [2,3,0,1]
#else
__device__ inline int dxor1(int v){ return __shfl_xor(v, 1, 64); }
__device__ inline int dxor2(int v){ return __shfl_xor(v, 2, 64); }
#endif

#if __has_builtin(__builtin_amdgcn_permlane16_swap)
__device__ inline int x16sum_i(int c){
  auto p = __builtin_amdgcn_permlane16_swap((unsigned)c, (unsigned)c, false, false);
  return (int)p[0] + (int)p[1];
}
__device__ inline int x16min_i(int c){
  auto p = __builtin_amdgcn_permlane16_swap((unsigned)c, (unsigned)c, false, false);
  return min((int)p[0], (int)p[1]);
}
__device__ inline int x16max_i(int c){
  auto p = __builtin_amdgcn_permlane16_swap((unsigned)c, (unsigned)c, false, false);
  return max((int)p[0], (int)p[1]);
}
__device__ inline float x16sum_f(float v){
  auto p = __builtin_amdgcn_permlane16_swap(__float_as_uint(v), __float_as_uint(v), false, false);
  return __uint_as_float(p[0]) + __uint_as_float(p[1]);
}
#else
__device__ inline int   x16sum_i(int c){ return c + __shfl_xor(c, 16, 64); }
__device__ inline int   x16min_i(int c){ return min(c, __shfl_xor(c, 16, 64)); }
__device__ inline int   x16max_i(int c){ return max(c, __shfl_xor(c, 16, 64)); }
__device__ inline float x16sum_f(float v){ return v + __shfl_xor(v, 16, 64); }
#endif

__device__ inline int ssum8_i(int c){ c += dxor1(c); c += dxor2(c); return x16sum_i(c); }
__device__ inline int smin8_i(int c){ c = min(c, dxor1(c)); c = min(c, dxor2(c)); return x16min_i(c); }
__device__ inline int smax8_i(int c){ c = max(c, dxor1(c)); c = max(c, dxor2(c)); return x16max_i(c); }
__device__ inline float ssum8_f(float v){
  v += __int_as_float(dxor1(__float_as_int(v)));
  v += __int_as_float(dxor2(__float_as_int(v)));
  return x16sum_f(v);
}

// async 16B global->LDS: lds dst is WAVE-UNIFORM base, HW adds lane*16
__device__ inline void cp16(void* lds_uniform, const void* g){
  __builtin_amdgcn_global_load_lds(
    (const __attribute__((address_space(1))) unsigned int*)g,
    (__attribute__((address_space(3))) unsigned int*)lds_uniform, 16, 0, 0);
}

// ---------- K0: normalize image features (32x512) ----------
__global__ void k_img(const float* __restrict__ X, float* __restrict__ imgn){
  int b = blockIdx.x, lane = threadIdx.x;
  const float* src = X + (size_t)b*512 + lane*8;
  float4 a = *(const float4*)src;
  float4 c = *(const float4*)(src+4);
  float ss = a.x*a.x+a.y*a.y+a.z*a.z+a.w*a.w + c.x*c.x+c.y*c.y+c.z*c.z+c.w*c.w;
  ss = wsum(ss);
  float inv = 1.0f/sqrtf(ss);
  float* dst = imgn + (size_t)b*512 + lane*8;
  float4 o0 = {a.x*inv,a.y*inv,a.z*inv,a.w*inv};
  float4 o1 = {c.x*inv,c.y*inv,c.z*inv,c.w*inv};
  *(float4*)dst = o0; *(float4*)(dst+4) = o1;
}

// ---------- K1: normalize txt; bf16 K-chunked TXT[kc][cn(51008)][32]; invn[n*1000+c] ----------
__global__ void k_txt(const float* __restrict__ X, u16* __restrict__ TXT, float* __restrict__ invn){
  int cn = blockIdx.x, lane = threadIdx.x;
  int kc = lane>>2, kk8 = (lane&3)*8;
  size_t dstE = ((size_t)kc*51008 + cn)*32 + kk8;
  if (cn >= 51000){
    uint4 z = {0,0,0,0};
    *(uint4*)(TXT + dstE) = z;
    return;
  }
  int c = cn/51, n = cn - c*51;
  const float* src = X + ((size_t)n*1000 + c)*512 + lane*8;
  float4 a = *(const float4*)src;
  float4 d = *(const float4*)(src+4);
  float ss = a.x*a.x+a.y*a.y+a.z*a.z+a.w*a.w + d.x*d.x+d.y*d.y+d.z*d.z+d.w*d.w;
  ss = wsum(ss);
  float inv = 1.0f/sqrtf(ss);
  u16 h0=f2bf(a.x*inv),h1=f2bf(a.y*inv),h2=f2bf(a.z*inv),h3=f2bf(a.w*inv);
  u16 h4=f2bf(d.x*inv),h5=f2bf(d.y*inv),h6=f2bf(d.z*inv),h7=f2bf(d.w*inv);
  uint4 o;
  o.x = (unsigned)h0 | ((unsigned)h1<<16);
  o.y = (unsigned)h2 | ((unsigned)h3<<16);
  o.z = (unsigned)h4 | ((unsigned)h5<<16);
  o.w = (unsigned)h6 | ((unsigned)h7<<16);
  *(uint4*)(TXT + dstE) = o;
  if (lane==0) invn[(size_t)n*1000 + c] = inv;
}

// ---------- K2: mean_txt[c] = l2norm( sum_n txt_n[c] ) ----------
__global__ void k_mean(const float* __restrict__ X, const float* __restrict__ invn, float* __restrict__ MT){
  int c = blockIdx.x, tid = threadIdx.x, lane = tid&63, wv = tid>>6;
  __shared__ float sinv[51];
  __shared__ float red[4];
  if (tid < 51) sinv[tid] = invn[(size_t)tid*1000 + c];
  __syncthreads();
  int d0 = tid*2;
  float sx=0.f, sy=0.f;
  for (int n=0;n<51;++n){
    const float2 x = *(const float2*)(X + ((size_t)n*1000 + c)*512 + d0);
    float iv = sinv[n];
    sx += x.x*iv; sy += x.y*iv;
  }
  float ss = sx*sx + sy*sy;
  ss = wsum(ss);
  if (lane==0) red[wv] = ss;
  __syncthreads();
  float tot = red[0]+red[1]+red[2]+red[3];
  float inv = 1.0f/sqrtf(tot);
  float2 o = {sx*inv, sy*inv};
  *(float2*)(MT + (size_t)c*512 + d0) = o;
}

// ---------- K3: v[c,n] = softmax_n( TEMP * mean_txt[c].txt[n,c] ) ----------
__global__ void k_v(const u16* __restrict__ TXT, const float* __restrict__ MT, float* __restrict__ vbuf){
  int c = blockIdx.x, lane = threadIdx.x;
  __shared__ float lg[51];
  const float* mp = MT + (size_t)c*512 + lane*8;
  float4 m0 = *(const float4*)mp;
  float4 m1 = *(const float4*)(mp+4);
  int kc = lane>>2, kk8 = (lane&3)*8;
  for (int n=0;n<51;++n){
    size_t e = ((size_t)kc*51008 + (size_t)(c*51+n))*32 + kk8;
    uint4 q = *(const uint4*)(TXT + e);
    float d = bfl(q.x)*m0.x + bfh(q.x)*m0.y + bfl(q.y)*m0.z + bfh(q.y)*m0.w
            + bfl(q.z)*m1.x + bfh(q.z)*m1.y + bfl(q.w)*m1.z + bfh(q.w)*m1.w;
    d = wsum(d);
    if (lane==0) lg[n] = d;
  }
  __syncthreads();
  float val = (lane<51) ? lg[lane] : -1e30f;
  float mx = wmax(val);
  float e = (lane<51) ? expf(TEMP*(val-mx)) : 0.f;
  float s = wsum(e);
  if (lane<51) vbuf[(size_t)c*51 + lane] = e/s;
}

// ---------- K4: bias[b,c] = base_logits ----------
__global__ void k_base(const float* __restrict__ imgn, const float* __restrict__ MT, float* __restrict__ bias){
  int c = blockIdx.x, lane = threadIdx.x;
  const float* mp = MT + (size_t)c*512 + lane*8;
  float4 m0 = *(const float4*)mp;
  float4 m1 = *(const float4*)(mp+4);
  for (int b=0;b<32;++b){
    const float* ip = imgn + (size_t)b*512 + lane*8;
    float4 i0 = *(const float4*)ip;
    float4 i1 = *(const float4*)(ip+4);
    float d = i0.x*m0.x+i0.y*m0.y+i0.z*m0.z+i0.w*m0.w
            + i1.x*m1.x+i1.y*m1.y+i1.z*m1.z+i1.w*m1.w;
    d = wsum(d);
    if (lane==0) bias[(size_t)b*1000 + c] = d;
  }
}

// ---------- K5: normalize loc; LOC[b][kc][m(224)][32] bf16; ew[b,m] (0 for m>=196) ----------
__global__ void k_loc(const float* __restrict__ L, const float* __restrict__ imgn,
                      u16* __restrict__ LOC, float* __restrict__ ewg){
  int m = blockIdx.x, b = blockIdx.y, lane = threadIdx.x;
  size_t dstE = ((size_t)(b*16 + (lane>>2))*224 + m)*32 + (lane&3)*8;
  if (m >= 196){
    uint4 z = {0,0,0,0};
    *(uint4*)(LOC + dstE) = z;
    if (lane==0) ewg[(size_t)b*224 + m] = 0.f;
    return;
  }
  const float* src = L + ((size_t)b*196 + m)*512 + lane*8;
  float4 a = *(const float4*)src;
  float4 d = *(const float4*)(src+4);
  const float* ip = imgn + (size_t)b*512 + lane*8;
  float4 i0 = *(const float4*)ip;
  float4 i1 = *(const float4*)(ip+4);
  float ss = a.x*a.x+a.y*a.y+a.z*a.z+a.w*a.w + d.x*d.x+d.y*d.y+d.z*d.z+d.w*d.w;
  float ws = a.x*i0.x+a.y*i0.y+a.z*i0.z+a.w*i0.w + d.x*i1.x+d.y*i1.y+d.z*i1.z+d.w*i1.w;
  ss = wsum(ss); ws = wsum(ws);
  float inv = 1.0f/sqrtf(ss);
  u16 h0=f2bf(a.x*inv),h1=f2bf(a.y*inv),h2=f2bf(a.z*inv),h3=f2bf(a.w*inv);
  u16 h4=f2bf(d.x*inv),h5=f2bf(d.y*inv),h6=f2bf(d.z*inv),h7=f2bf(d.w*inv);
  uint4 o;
  o.x = (unsigned)h0 | ((unsigned)h1<<16);
  o.y = (unsigned)h2 | ((unsigned)h3<<16);
  o.z = (unsigned)h4 | ((unsigned)h5<<16);
  o.w = (unsigned)h6 | ((unsigned)h7<<16);
  *(uint4*)(LOC + dstE) = o;
  if (lane==0) ewg[(size_t)b*224 + m] = expf(TEMP * ws * inv);
}

// ---------- K6: fused GEMM (MFMA bf16) + in-register top-50 + weighted sum ----------
// THIS ROUND: REVERT to the R8 structure (proven 850us) + data-derived first
// probe. R9 post-mortem: barrier-free direct-A regressed 850->1253 (MfmaUtil
// 12.7, VALU 38): removing LDS staging doubled TCP line-request traffic (A
// consumed by both wn-waves, 44 loads x 16 lines/kc/block) and removed the
// staging pipeline -> latency-bound. LDS staging was load-bearing for BW
// amortization, not just sharing. Restored: M-major waves (wm owns 4 m-tiles,
// wm=3: 2; wn: 32-col half), A via global_load_lds dbuf + per-kc barrier, B
// direct from L2, A-swizzle sigma(u)=u^((u>>3)&3) both-sides.
// NEW (epilogue trim; R8's bound was issue: VALU 64 + MFMA 20 = 84%):
//  * first threshold = 2nd-largest of 8 stratified samples (m=28*sub+12);
//    E[frac above 2nd-max of ~7] ~ 2/8 = 0.25 ~ 50/196 -> probe #1 lands near
//    count=50; many columns exact-exit immediately; Illinois works a narrow
//    bracket after. Cap 14 -> 1 peeled + 12.
//  * GE-direct count: (tm-1-k)>>15 accumulates -1 per key>=tm (saves the
//    28-minus correction; sentinels -16000 < tm always excluded).
// Epilogue layout unchanged: keys m-ordered in 4 slabs x [16 cols][116 u32];
// wave (wv>>1, wv&1) selects 8 cols x 8 lanes x 28 keys; sentinel pads at
// sub==7; 16-bit keys k=(int)(x*15360); DPP+permlane 8-lane reduces.
// acc[]/kk[] compile-time indices only (scratch-demotion trap).
__global__ __launch_bounds__(512,8) void k_main(const u16* __restrict__ TXT, const u16* __restrict__ LOC,
                                                const float* __restrict__ ewg, const float* __restrict__ vbuf,
                                                float* __restrict__ bias){
  __shared__ __align__(16) char smem[30592];   // A dbuf 28672 | key-exchange 4x7424B=29696 (overlaps) | ewl @29696
  const int tid = threadIdx.x, lane = tid & 63, wv = tid >> 6;   // 8 waves
  const int quad = lane >> 4, l16 = lane & 15;
  const int wm = wv >> 1, wn = wv & 1;         // wm: m-quarter (4 tiles; wm=3: 2), wn: 32-col half
  const int NT = (wm == 3) ? 2 : 4;
  const int lsw = lane ^ ((lane>>3)&3);        // stage-side swizzled source lane
  const int qsw = (quad ^ ((l16>>1)&3)) * 16;  // read-side swizzled slot byte offset
  const int sub = (lane & 3) | ((lane >> 2) & 4);        // selection: lane bits {0,1,4}
  const int col = ((lane >> 2) & 3) | ((lane >> 3) & 4); // selection: lane bits {2,3,5}

  // group swizzle: groups of 32 cn-tiles x 32 b; last group 29 x 32
  int id = blockIdx.x, b, cnt_;
  if (id < 24576){
    int g = id >> 10, r = id & 1023;
    b = r >> 5;  cnt_ = (g << 5) + (r & 31);
  } else {
    int r = id - 24576;
    b = r / 29;  cnt_ = 768 + r % 29;
  }
  const int cn0 = cnt_ * 64;

  // stage ew early (region disjoint from A dbuf/exchange; read after final K barrier)
  float* ewl = (float*)(smem + 29696);
  if (tid < 224) ewl[tid] = ewg[(size_t)b*224 + tid];

  const f32x4 zero = {0.f,0.f,0.f,0.f};
  f32x4 acc[4][2];
  #pragma unroll
  for (int t=0;t<4;++t){ acc[t][0]=zero; acc[t][1]=zero; }

  const u16* Abase = LOC + (size_t)(b*16)*224*32;
  char* Albd0 = smem;
  char* Albd1 = smem + 14336;

  auto stageA = [&](int kc, char* dst){
    const char* src = (const char*)(Abase + (size_t)kc*224*32);
    #pragma unroll
    for (int j=0;j<2;++j){
      int ch0 = j*512 + wv*64;                 // wave-uniform chunk base
      if (ch0 < 896)
        cp16(dst + (size_t)ch0*16, src + (size_t)(ch0 + lsw)*16);
    }
  };
  struct B2 { bf16x8 x, y; };
  auto loadB = [&](int kc)->B2{
    B2 r;
    size_t e = ((size_t)kc*51008 + (size_t)(cn0 + 32*wn + l16))*32 + quad*8;
    r.x = *(const bf16x8*)(TXT + e);
    r.y = *(const bf16x8*)(TXT + e + 16*32);
    return r;
  };
  auto domfma = [&](const char* Ab, B2 bb){
    #pragma unroll
    for (int t=0;t<4;++t){
      if (t < NT){   // wave-uniform branch (wm uniform per wave)
        bf16x8 af = *(const bf16x8*)(Ab + (size_t)(((4*wm + t)*16 + l16)*64) + qsw);
        acc[t][0] = __builtin_amdgcn_mfma_f32_16x16x32_bf16(af, bb.x, acc[t][0], 0,0,0);
        acc[t][1] = __builtin_amdgcn_mfma_f32_16x16x32_bf16(af, bb.y, acc[t][1], 0,0,0);
      }
    }
  };

  stageA(0, Albd0);
  __syncthreads();

  for (int kc = 0; kc < 16; ++kc){
    char* cur = (kc & 1) ? Albd1 : Albd0;
    char* nxt = (kc & 1) ? Albd0 : Albd1;
    B2 bb = loadB(kc);           // issued first: vmcnt-wait for B won't drain cp16s below
    if (kc < 15) stageA(kc+1, nxt);
    domfma(cur, bb);
    __syncthreads();
  }

  // ---- epilogue: pack keys to LDS in m-order, re-read split by columns ----
  // slab s = 2wn+n in [0,4): [16 cols][116 u32]; u32 idx within col = m/2.
  const float KSC = 15360.0f;
  {
    #pragma unroll
    for (int n=0;n<2;++n){
      unsigned* wr = (unsigned*)(void*)smem + (size_t)((2*wn + n)*1856) + l16*116 + quad*2;
      #pragma unroll
      for (int t=0;t<4;++t){
        if (t < NT){
          int a0 = (int)(acc[t][n][0]*KSC), a1 = (int)(acc[t][n][1]*KSC);
          int a2 = (int)(acc[t][n][2]*KSC), a3 = (int)(acc[t][n][3]*KSC);
          uint2 o; o.x = (unsigned)((a0 & 0xffff) | (a1<<16)); o.y = (unsigned)((a2 & 0xffff) | (a3<<16));
          *(uint2*)(wr + (4*wm + t)*8) = o;
        }
      }
    }
  }
  __syncthreads();

  int kk[7][2];
  {
    const unsigned* rd = (const unsigned*)(void*)smem + (size_t)((wv>>1)*1856) + ((wv&1)*8 + col)*116 + sub*14;
    #pragma unroll
    for (int j=0;j<7;++j){
      uint2 q = *(const uint2*)(rd + 2*j);
      kk[j][0] = (int)q.x;
      kk[j][1] = (int)q.y;
    }
  }
  // pads: m>=196 <=> u32 idx>=98 <=> sub==7 (idx = sub*14 + [0,14)) -> whole lane
  const int PKPK = (int)0xC180C180;  // two packed -16000 sentinels (below all real keys)
  if (sub == 7){
    #pragma unroll
    for (int j=0;j<7;++j){ kk[j][0] = PKPK; kk[j][1] = PKPK; }
  }

  // ---- bracket (sub<7 lanes cover exactly m=0..195, all real) ----
  s16x2 vmn = as_s16x2(kk[0][0]), vmx = vmn;
  #pragma unroll
  for (int j=0;j<7;++j){
    #pragma unroll
    for (int i=0;i<2;++i){
      vmn = pkmin2(vmn, as_s16x2(kk[j][i]));
      vmx = pkmax2(vmx, as_s16x2(kk[j][i]));
    }
  }
  int kmn = min((int)vmn.x, (int)vmn.y);
  int kmx = max((int)vmx.x, (int)vmx.y);
  if (sub == 7){ kmn = 32000; kmx = -32000; }   // exclude sentinel lane from bracket
  kmn = smin8_i(kmn);
  kmx = smax8_i(kmx);
  int lo = kmn - 1, hi = kmx + 1;   // cnt(lo)=196>=50, cnt(hi)=0<50; tm>lo>-16000 -> pads never counted

  // ---- count_ge(tm): # keys >= tm in this column (sentinels self-excluded) ----
  auto count_ge = [&](int tm)->int{
    int t1 = tm - 1;
    s16x2 tmv = as_s16x2((t1 & 0xffff) | (t1 << 16));
    s16x2 ca = {0,0};
    #pragma unroll
    for (int j=0;j<7;++j){
      ca = ca + ((tmv - as_s16x2(kk[j][0])) >> 15);   // -1 per key >= tm
      ca = ca + ((tmv - as_s16x2(kk[j][1])) >> 15);
    }
    return ssum8_i(-((int)ca.x + (int)ca.y));
  };

  // ---- peeled probe #1: 2nd-largest of 8 stratified samples (m = 28*sub+12) ----
  int samp = (kk[3][0]<<16)>>16;            // sext low key of kk[3][0]
  if (sub == 7) samp = -32768;              // sentinel lane out of sampling
  int mx1 = smax8_i(samp);
  int m2  = smax8_i(samp == mx1 ? -32768 : samp);
  int tm0 = min(hi - 1, max(lo + 1, m2));
  int c0  = count_ge(tm0);

  float flo = 146.0f, fhi = -50.0f;         // counts-50 at lo/hi
  int side;
  if (c0 >= 50){ lo = tm0; flo = (float)(c0 - 50); side = 1; }
  else         { hi = tm0; fhi = (float)(c0 - 50); side = -1; }
  bool done = (c0 == 50) || ((hi - lo) <= 1);

  // ---- integer false position (Illinois) on packed counts ----
  #pragma unroll 1
  for (int it = 0; it < 12; ++it){
    if (__all(done)) break;
    float fr = flo * __builtin_amdgcn_rcpf(flo - fhi);
    fr = fminf(fmaxf(fr, 0.04f), 0.96f);
    int tm = lo + (int)(fr * (float)(hi - lo));
    tm = (tm <= lo) ? (lo + 1) : ((tm >= hi) ? (hi - 1) : tm);

    int c = count_ge(tm);
    bool ge = (c >= 50);
    if (!done){
      if (ge){ fhi = (side==1)  ? fhi*0.5f : fhi; flo = (float)(c-50); lo = tm; side = 1; }
      else   { flo = (side==-1) ? flo*0.5f : flo; fhi = (float)(c-50); hi = tm; side = -1; }
    }
    done = done || (c == 50) || ((hi - lo) <= 1);
  }
  const int thr = lo;

  // ---- final weighted sum: x = key/15360; ew via m = 28*sub + 4j + {0..3} ----
  float num = 0.f, den = 0.f;
  #pragma unroll
  for (int j=0;j<7;++j){
    float2 e0 = *(const float2*)(ewl + 28*sub + 4*j);
    float2 e1 = *(const float2*)(ewl + 28*sub + 4*j + 2);
    int a0 = (kk[j][0]<<16)>>16, a1 = kk[j][0]>>16;
    int a2 = (kk[j][1]<<16)>>16, a3 = kk[j][1]>>16;
    if (a0 >= thr){ num = fmaf((float)a0, e0.x, num); den += e0.x; }
    if (a1 >= thr){ num = fmaf((float)a1, e0.y, num); den += e0.y; }
    if (a2 >= thr){ num = fmaf((float)a2, e1.x, num); den += e1.x; }
    if (a3 >= thr){ num = fmaf((float)a3, e1.y, num); den += e1.y; }
  }
  num = ssum8_f(num);
  den = ssum8_f(den);

  int cn = cn0 + (wv>>1)*16 + (wv&1)*8 + col;
  if (sub == 0 && cn < 51000){
    int c = cn/51;
    atomicAdd(bias + (size_t)b*1000 + c, vbuf[cn]*(num/(den*KSC)));
  }
}

// ---------- K7: out = fp32( exp(logit_scale) * bias ) ----------
__global__ void k_out(const float* __restrict__ bias, const float* __restrict__ ls, float* __restrict__ out){
  int i = blockIdx.x*256 + threadIdx.x;
  if (i < 32000){
    float sc = expf(ls[0]);
    out[i] = sc * bias[i];
  }
}

// ---------- launch ----------
extern "C" void kernel_launch(void* const* d_in, const int* in_sizes, int n_in,
                              void* d_out, int out_size, void* d_ws, size_t ws_size,
                              hipStream_t stream) {
  const float* img = (const float*)d_in[0];
  const float* loc = (const float*)d_in[1];
  const float* txt = (const float*)d_in[2];
  const float* ls  = (const float*)d_in[3];
  char* ws = (char*)d_ws;
  float* imgn = (float*)(ws + 0);            //  65536
  float* MT   = (float*)(ws + 65536);        //  2048000
  float* invn = (float*)(ws + 2113536);      //  204032
  float* vbuf = (float*)(ws + 2317568);      //  204032
  float* ewg  = (float*)(ws + 2521600);      //  28672
  float* bias = (float*)(ws + 2550272);      //  128000
  u16*   TXT  = (u16*)  (ws + 2678272);      //  52232192
  u16*   LOC  = (u16*)  (ws + 54910464);     //  7340032

  k_img <<<dim3(32),      dim3(64),  0, stream>>>(img, imgn);
  k_txt <<<dim3(51008),   dim3(64),  0, stream>>>(txt, TXT, invn);
  k_mean<<<dim3(1000),    dim3(256), 0, stream>>>(txt, invn, MT);
  k_v   <<<dim3(1000),    dim3(64),  0, stream>>>(TXT, MT, vbuf);
  k_base<<<dim3(1000),    dim3(64),  0, stream>>>(imgn, MT, bias);
  k_loc <<<dim3(224,32),  dim3(64),  0, stream>>>(loc, imgn, LOC, ewg);
  k_main<<<dim3(25504),   dim3(512), 0, stream>>>(TXT, LOC, ewg, vbuf, bias);
  k_out <<<dim3(125),     dim3(256), 0, stream>>>(bias, ls, (float*)d_out);
}

// Round 12
// 965.003 us; speedup vs baseline: 1.4413x; 1.0432x over previous
//
#include <hip/hip_runtime.h>
#include <stdint.h>

typedef __bf16  bf16x8 __attribute__((ext_vector_type(8)));
typedef float   f32x4  __attribute__((ext_vector_type(4)));
typedef short   s16x2  __attribute__((ext_vector_type(2)));
typedef unsigned short u16;

#define TEMP 5.0f

// ---------- helpers ----------
__device__ inline float wsum(float v){
  #pragma unroll
  for (int off=32; off; off>>=1) v += __shfl_xor(v, off, 64);
  return v;
}
__device__ inline float wmax(float v){
  #pragma unroll
  for (int off=32; off; off>>=1) v = fmaxf(v, __shfl_xor(v, off, 64));
  return v;
}
__device__ inline u16 f2bf(float f){               // RNE float->bf16
  unsigned u = __float_as_uint(f);
  u = u + 0x7fffu + ((u>>16)&1u);
  return (u16)(u>>16);
}
__device__ inline float bfl(unsigned u){ return __uint_as_float(u<<16); }
__device__ inline float bfh(unsigned u){ return __uint_as_float(u & 0xffff0000u); }

__device__ inline s16x2 as_s16x2(int v){ union{int i; s16x2 v;} u; u.i=v; return u.v; }

__device__ inline s16x2 pkmax2(s16x2 a, s16x2 b){
  s16x2 r; r.x = a.x > b.x ? a.x : b.x; r.y = a.y > b.y ? a.y : b.y; return r;
}

// ---- 4-lane quad-group reduce over lane bits {4,5}: permlane16_swap (^16)
// + permlane32_swap (^32). Pure VALU, no LDS round-trips.
#if __has_builtin(__builtin_amdgcn_permlane16_swap) && __has_builtin(__builtin_amdgcn_permlane32_swap)
__device__ inline int x16sum_i(int c){
  auto p = __builtin_amdgcn_permlane16_swap((unsigned)c, (unsigned)c, false, false);
  return (int)p[0] + (int)p[1];
}
__device__ inline int x16max_i(int c){
  auto p = __builtin_amdgcn_permlane16_swap((unsigned)c, (unsigned)c, false, false);
  return max((int)p[0], (int)p[1]);
}
__device__ inline float x16sum_f(float v){
  auto p = __builtin_amdgcn_permlane16_swap(__float_as_uint(v), __float_as_uint(v), false, false);
  return __uint_as_float(p[0]) + __uint_as_float(p[1]);
}
__device__ inline int x32sum_i(int c){
  auto p = __builtin_amdgcn_permlane32_swap((unsigned)c, (unsigned)c, false, false);
  return (int)p[0] + (int)p[1];
}
__device__ inline int x32max_i(int c){
  auto p = __builtin_amdgcn_permlane32_swap((unsigned)c, (unsigned)c, false, false);
  return max((int)p[0], (int)p[1]);
}
__device__ inline float x32sum_f(float v){
  auto p = __builtin_amdgcn_permlane32_swap(__float_as_uint(v), __float_as_uint(v), false, false);
  return __uint_as_float(p[0]) + __uint_as_float(p[1]);
}
#else
__device__ inline int   x16sum_i(int c){ return c + __shfl_xor(c, 16, 64); }
__device__ inline int   x16max_i(int c){ return max(c, __shfl_xor(c, 16, 64)); }
__device__ inline float x16sum_f(float v){ return v + __shfl_xor(v, 16, 64); }
__device__ inline int   x32sum_i(int c){ return c + __shfl_xor(c, 32, 64); }
__device__ inline int   x32max_i(int c){ return max(c, __shfl_xor(c, 32, 64)); }
__device__ inline float x32sum_f(float v){ return v + __shfl_xor(v, 32, 64); }
#endif

__device__ inline int   qsum4_i(int c){ return x32sum_i(x16sum_i(c)); }
__device__ inline int   qmax4_i(int c){ return x32max_i(x16max_i(c)); }
__device__ inline float qsum4_f(float v){ return x32sum_f(x16sum_f(v)); }

// async 16B global->LDS: lds dst is WAVE-UNIFORM base, HW adds lane*16
__device__ inline void cp16(void* lds_uniform, const void* g){
  __builtin_amdgcn_global_load_lds(
    (const __attribute__((address_space(1))) unsigned int*)g,
    (__attribute__((address_space(3))) unsigned int*)lds_uniform, 16, 0, 0);
}

// ---------- K0: normalize image features (32x512) ----------
__global__ void k_img(const float* __restrict__ X, float* __restrict__ imgn){
  int b = blockIdx.x, lane = threadIdx.x;
  const float* src = X + (size_t)b*512 + lane*8;
  float4 a = *(const float4*)src;
  float4 c = *(const float4*)(src+4);
  float ss = a.x*a.x+a.y*a.y+a.z*a.z+a.w*a.w + c.x*c.x+c.y*c.y+c.z*c.z+c.w*c.w;
  ss = wsum(ss);
  float inv = 1.0f/sqrtf(ss);
  float* dst = imgn + (size_t)b*512 + lane*8;
  float4 o0 = {a.x*inv,a.y*inv,a.z*inv,a.w*inv};
  float4 o1 = {c.x*inv,c.y*inv,c.z*inv,c.w*inv};
  *(float4*)dst = o0; *(float4*)(dst+4) = o1;
}

// ---------- K1: normalize txt; bf16 K-chunked TXT[kc][cn(51008)][32]; invn[n*1000+c] ----------
__global__ void k_txt(const float* __restrict__ X, u16* __restrict__ TXT, float* __restrict__ invn){
  int cn = blockIdx.x, lane = threadIdx.x;
  int kc = lane>>2, kk8 = (lane&3)*8;
  size_t dstE = ((size_t)kc*51008 + cn)*32 + kk8;
  if (cn >= 51000){
    uint4 z = {0,0,0,0};
    *(uint4*)(TXT + dstE) = z;
    return;
  }
  int c = cn/51, n = cn - c*51;
  const float* src = X + ((size_t)n*1000 + c)*512 + lane*8;
  float4 a = *(const float4*)src;
  float4 d = *(const float4*)(src+4);
  float ss = a.x*a.x+a.y*a.y+a.z*a.z+a.w*a.w + d.x*d.x+d.y*d.y+d.z*d.z+d.w*d.w;
  ss = wsum(ss);
  float inv = 1.0f/sqrtf(ss);
  u16 h0=f2bf(a.x*inv),h1=f2bf(a.y*inv),h2=f2bf(a.z*inv),h3=f2bf(a.w*inv);
  u16 h4=f2bf(d.x*inv),h5=f2bf(d.y*inv),h6=f2bf(d.z*inv),h7=f2bf(d.w*inv);
  uint4 o;
  o.x = (unsigned)h0 | ((unsigned)h1<<16);
  o.y = (unsigned)h2 | ((unsigned)h3<<16);
  o.z = (unsigned)h4 | ((unsigned)h5<<16);
  o.w = (unsigned)h6 | ((unsigned)h7<<16);
  *(uint4*)(TXT + dstE) = o;
  if (lane==0) invn[(size_t)n*1000 + c] = inv;
}

// ---------- K2: mean_txt[c] = l2norm( sum_n txt_n[c] ) ----------
__global__ void k_mean(const float* __restrict__ X, const float* __restrict__ invn, float* __restrict__ MT){
  int c = blockIdx.x, tid = threadIdx.x, lane = tid&63, wv = tid>>6;
  __shared__ float sinv[51];
  __shared__ float red[4];
  if (tid < 51) sinv[tid] = invn[(size_t)tid*1000 + c];
  __syncthreads();
  int d0 = tid*2;
  float sx=0.f, sy=0.f;
  for (int n=0;n<51;++n){
    const float2 x = *(const float2*)(X + ((size_t)n*1000 + c)*512 + d0);
    float iv = sinv[n];
    sx += x.x*iv; sy += x.y*iv;
  }
  float ss = sx*sx + sy*sy;
  ss = wsum(ss);
  if (lane==0) red[wv] = ss;
  __syncthreads();
  float tot = red[0]+red[1]+red[2]+red[3];
  float inv = 1.0f/sqrtf(tot);
  float2 o = {sx*inv, sy*inv};
  *(float2*)(MT + (size_t)c*512 + d0) = o;
}

// ---------- K3: v[c,n] = softmax_n( TEMP * mean_txt[c].txt[n,c] ) ----------
__global__ void k_v(const u16* __restrict__ TXT, const float* __restrict__ MT, float* __restrict__ vbuf){
  int c = blockIdx.x, lane = threadIdx.x;
  __shared__ float lg[51];
  const float* mp = MT + (size_t)c*512 + lane*8;
  float4 m0 = *(const float4*)mp;
  float4 m1 = *(const float4*)(mp+4);
  int kc = lane>>2, kk8 = (lane&3)*8;
  for (int n=0;n<51;++n){
    size_t e = ((size_t)kc*51008 + (size_t)(c*51+n))*32 + kk8;
    uint4 q = *(const uint4*)(TXT + e);
    float d = bfl(q.x)*m0.x + bfh(q.x)*m0.y + bfl(q.y)*m0.z + bfh(q.y)*m0.w
            + bfl(q.z)*m1.x + bfh(q.z)*m1.y + bfl(q.w)*m1.z + bfh(q.w)*m1.w;
    d = wsum(d);
    if (lane==0) lg[n] = d;
  }
  __syncthreads();
  float val = (lane<51) ? lg[lane] : -1e30f;
  float mx = wmax(val);
  float e = (lane<51) ? expf(TEMP*(val-mx)) : 0.f;
  float s = wsum(e);
  if (lane<51) vbuf[(size_t)c*51 + lane] = e/s;
}

// ---------- K4: bias[b,c] = base_logits ----------
__global__ void k_base(const float* __restrict__ imgn, const float* __restrict__ MT, float* __restrict__ bias){
  int c = blockIdx.x, lane = threadIdx.x;
  const float* mp = MT + (size_t)c*512 + lane*8;
  float4 m0 = *(const float4*)mp;
  float4 m1 = *(const float4*)(mp+4);
  for (int b=0;b<32;++b){
    const float* ip = imgn + (size_t)b*512 + lane*8;
    float4 i0 = *(const float4*)ip;
    float4 i1 = *(const float4*)(ip+4);
    float d = i0.x*m0.x+i0.y*m0.y+i0.z*m0.z+i0.w*m0.w
            + i1.x*m1.x+i1.y*m1.y+i1.z*m1.z+i1.w*m1.w;
    d = wsum(d);
    if (lane==0) bias[(size_t)b*1000 + c] = d;
  }
}

// ---------- K5: normalize loc; LOC[b][kc][m(224)][32] bf16; ew[b,m] (0 for m>=196) ----------
__global__ void k_loc(const float* __restrict__ L, const float* __restrict__ imgn,
                      u16* __restrict__ LOC, float* __restrict__ ewg){
  int m = blockIdx.x, b = blockIdx.y, lane = threadIdx.x;
  size_t dstE = ((size_t)(b*16 + (lane>>2))*224 + m)*32 + (lane&3)*8;
  if (m >= 196){
    uint4 z = {0,0,0,0};
    *(uint4*)(LOC + dstE) = z;
    if (lane==0) ewg[(size_t)b*224 + m] = 0.f;
    return;
  }
  const float* src = L + ((size_t)b*196 + m)*512 + lane*8;
  float4 a = *(const float4*)src;
  float4 d = *(const float4*)(src+4);
  const float* ip = imgn + (size_t)b*512 + lane*8;
  float4 i0 = *(const float4*)ip;
  float4 i1 = *(const float4*)(ip+4);
  float ss = a.x*a.x+a.y*a.y+a.z*a.z+a.w*a.w + d.x*d.x+d.y*d.y+d.z*d.z+d.w*d.w;
  float ws = a.x*i0.x+a.y*i0.y+a.z*i0.z+a.w*i0.w + d.x*i1.x+d.y*i1.y+d.z*i1.z+d.w*i1.w;
  ss = wsum(ss); ws = wsum(ws);
  float inv = 1.0f/sqrtf(ss);
  u16 h0=f2bf(a.x*inv),h1=f2bf(a.y*inv),h2=f2bf(a.z*inv),h3=f2bf(a.w*inv);
  u16 h4=f2bf(d.x*inv),h5=f2bf(d.y*inv),h6=f2bf(d.z*inv),h7=f2bf(d.w*inv);
  uint4 o;
  o.x = (unsigned)h0 | ((unsigned)h1<<16);
  o.y = (unsigned)h2 | ((unsigned)h3<<16);
  o.z = (unsigned)h4 | ((unsigned)h5<<16);
  o.w = (unsigned)h6 | ((unsigned)h7<<16);
  *(uint4*)(LOC + dstE) = o;
  if (lane==0) ewg[(size_t)b*224 + m] = expf(TEMP * ws * inv);
}

// ---------- K6: fused GEMM (MFMA bf16) + in-register top-50 + weighted sum ----------
// R11 was an infra failure (container died twice, no measurement) -- this is an
// UNCHANGED resubmit of the R11 kernel. Theory (from R10 post-mortem) stands:
// resurrect the R4 4-wave K-loop geometry (best-ever 817us) WITHOUT its spills.
// k_main runs at 440TF = 18% MFMA peak, feeding-limited; VALU+MFMA ~ issue-
// saturated. The 4-wave config (wave = 112 rows x 32 cols) has HALF the B
// L1-traffic (2x redundancy vs 4x), 14 MFMA/wave/kc (vs 8), and half the
// K-loop addressing replicas. R5's de-spill attempt failed ONLY because it
// kept the cross-kc B-prefetch (16 regs); R8 proved per-kc B-load works in
// this staged loop. K-loop liveness: acc 56 + bb 8 + addr ~20 = ~84 <= 96 ->
// (256,5) spill-free. KEY CHECK: WRITE_SIZE >300MB = still spilling = dead.
// Epilogue (R10 machinery re-split for 4 waves): keys m-ordered in 4 slabs x
// [16 cols][116 u32]; wave wv selects slab wv: 16 cols x 4 lanes/col
// (col=l16, sub=quad), 28 u32 keys/lane; pads (idx>=98) land in quad==3 j>=7
// -> lane-uniform sentinels; fixed lo=-15600 (below all real keys, above
// sentinel -16000) kills the min-bracket; peeled 2nd-max-of-4-samples first
// probe; integer Illinois false-position (exact c==50 / width<=1 exits);
// quad-group reduces via permlane16+32 swaps. 16-bit keys k=(int)(x*15360).
// (History: A-swizzle sigma(u)=u^((u>>3)&3) both-sides on global_load_lds.)
// acc[]/kk[] compile-time indices only (scratch-demotion trap).
__global__ __launch_bounds__(256,5) void k_main(const u16* __restrict__ TXT, const u16* __restrict__ LOC,
                                                const float* __restrict__ ewg, const float* __restrict__ vbuf,
                                                float* __restrict__ bias){
  __shared__ __align__(16) char smem[30592];   // A dbuf 28672 | key-exchange 4x7424B=29696 (overlaps) | ewl @29696
  const int tid = threadIdx.x, lane = tid & 63, wv = tid >> 6;   // 4 waves
  const int quad = lane >> 4, l16 = lane & 15;
  const int ms = wv >> 1, ns = wv & 1;         // ms: m-half (7 tiles), ns: 32-col half
  const int lsw = lane ^ ((lane>>3)&3);        // stage-side swizzled source lane
  const int qsw = (quad ^ ((l16>>1)&3)) * 16;  // read-side swizzled slot byte offset

  // group swizzle: groups of 32 cn-tiles x 32 b; last group 29 x 32
  int id = blockIdx.x, b, cnt_;
  if (id < 24576){
    int g = id >> 10, r = id & 1023;
    b = r >> 5;  cnt_ = (g << 5) + (r & 31);
  } else {
    int r = id - 24576;
    b = r / 29;  cnt_ = 768 + r % 29;
  }
  const int cn0 = cnt_ * 64;

  // stage ew early (region disjoint from A dbuf/exchange; read after final K barrier)
  float* ewl = (float*)(smem + 29696);
  if (tid < 224) ewl[tid] = ewg[(size_t)b*224 + tid];

  const f32x4 zero = {0.f,0.f,0.f,0.f};
  f32x4 acc[7][2];
  #pragma unroll
  for (int t=0;t<7;++t){ acc[t][0]=zero; acc[t][1]=zero; }

  const u16* Abase = LOC + (size_t)(b*16)*224*32;
  char* Albd0 = smem;
  char* Albd1 = smem + 14336;

  auto stageA = [&](int kc, char* dst){
    const char* src = (const char*)(Abase + (size_t)kc*224*32);
    #pragma unroll
    for (int j=0;j<4;++j){
      int ch0 = j*256 + wv*64;                 // wave-uniform chunk base
      if (ch0 < 896)
        cp16(dst + (size_t)ch0*16, src + (size_t)(ch0 + lsw)*16);
    }
  };
  struct B2 { bf16x8 x, y; };
  auto loadB = [&](int kc)->B2{
    B2 r;
    size_t e = ((size_t)kc*51008 + (size_t)(cn0 + 32*ns + l16))*32 + quad*8;
    r.x = *(const bf16x8*)(TXT + e);
    r.y = *(const bf16x8*)(TXT + e + 16*32);
    return r;
  };
  auto domfma = [&](const char* Ab, B2 bb){
    #pragma unroll
    for (int t=0;t<7;++t){
      bf16x8 af = *(const bf16x8*)(Ab + (size_t)((112*ms + 16*t + l16)*64) + qsw);
      acc[t][0] = __builtin_amdgcn_mfma_f32_16x16x32_bf16(af, bb.x, acc[t][0], 0,0,0);
      acc[t][1] = __builtin_amdgcn_mfma_f32_16x16x32_bf16(af, bb.y, acc[t][1], 0,0,0);
    }
  };

  stageA(0, Albd0);
  __syncthreads();

  for (int kc = 0; kc < 16; ++kc){
    char* cur = (kc & 1) ? Albd1 : Albd0;
    char* nxt = (kc & 1) ? Albd0 : Albd1;
    B2 bb = loadB(kc);           // issued first: vmcnt-wait for B won't drain cp16s below
    if (kc < 15) stageA(kc+1, nxt);
    domfma(cur, bb);
    __syncthreads();
  }

  // ---- epilogue: pack keys to LDS in m-order, re-read split by columns ----
  // slab s = 2ns+z in [0,4): [16 cols][116 u32]; u32 idx within col = m/2;
  // writer uint2 idx0 = (7ms+t)*8 + quad*2.
  const float KSC = 15360.0f;
  {
    #pragma unroll
    for (int z=0;z<2;++z){
      unsigned* wr = (unsigned*)(void*)smem + (size_t)((2*ns + z)*1856) + l16*116 + quad*2;
      #pragma unroll
      for (int t=0;t<7;++t){
        int a0 = (int)(acc[t][z][0]*KSC), a1 = (int)(acc[t][z][1]*KSC);
        int a2 = (int)(acc[t][z][2]*KSC), a3 = (int)(acc[t][z][3]*KSC);
        uint2 o; o.x = (unsigned)((a0 & 0xffff) | (a1<<16)); o.y = (unsigned)((a2 & 0xffff) | (a3<<16));
        *(uint2*)(wr + (7*ms + t)*8) = o;
      }
    }
  }
  __syncthreads();

  // reader: wave wv owns slab wv; col = l16, 4 lanes/col (sub = quad),
  // per lane u32 idx = 28*quad + [0,28) read as 14 uint2.
  int kk[14][2];
  {
    const unsigned* rd = (const unsigned*)(void*)smem + (size_t)(wv*1856) + l16*116 + quad*28;
    #pragma unroll
    for (int j=0;j<14;++j){
      uint2 q = *(const uint2*)(rd + 2*j);
      kk[j][0] = (int)q.x;
      kk[j][1] = (int)q.y;
    }
  }
  // pads: m>=196 <=> u32 idx>=98 <=> quad==3 && local u>=14 <=> j>=7
  const int PKPK = (int)0xC180C180;  // two packed -16000 sentinels (below all real keys)
  if (quad == 3){
    #pragma unroll
    for (int j=7;j<14;++j){ kk[j][0] = PKPK; kk[j][1] = PKPK; }
  }

  // ---- bracket: hi from max (sentinels never max); lo fixed below all real keys ----
  s16x2 vmx = as_s16x2(kk[0][0]);
  #pragma unroll
  for (int j=0;j<14;++j){
    vmx = pkmax2(vmx, as_s16x2(kk[j][0]));
    vmx = pkmax2(vmx, as_s16x2(kk[j][1]));
  }
  int kmx = max((int)vmx.x, (int)vmx.y);
  kmx = qmax4_i(kmx);
  int lo = -15600, hi = kmx + 1;   // cnt(lo)=196>=50, cnt(hi)=0<50; tm>lo>-16000 -> pads never counted

  // ---- count_ge(tm): # keys >= tm in this column (sentinels self-excluded) ----
  auto count_ge = [&](int tm)->int{
    int t1 = tm - 1;
    s16x2 tmv = as_s16x2((t1 & 0xffff) | (t1 << 16));
    s16x2 ca = {0,0};
    #pragma unroll
    for (int j=0;j<14;++j){
      ca = ca + ((tmv - as_s16x2(kk[j][0])) >> 15);   // -1 per key >= tm
      ca = ca + ((tmv - as_s16x2(kk[j][1])) >> 15);
    }
    return qsum4_i(-((int)ca.x + (int)ca.y));
  };

  // ---- peeled probe #1: 2nd-largest of 4 stratified samples (m = 56*quad+12) ----
  int samp = (kk[3][0]<<16)>>16;            // idx 28*quad+6 -> always real (quad==3: idx 90 < 98)
  int mx1 = qmax4_i(samp);
  int m2  = qmax4_i(samp == mx1 ? -32768 : samp);
  int tm0 = min(hi - 1, max(lo + 1, m2));
  int c0  = count_ge(tm0);

  float flo = 146.0f, fhi = -50.0f;         // counts-50 at lo/hi
  int side;
  if (c0 >= 50){ lo = tm0; flo = (float)(c0 - 50); side = 1; }
  else         { hi = tm0; fhi = (float)(c0 - 50); side = -1; }
  bool done = (c0 == 50) || ((hi - lo) <= 1);

  // ---- integer false position (Illinois) on packed counts ----
  #pragma unroll 1
  for (int it = 0; it < 12; ++it){
    if (__all(done)) break;
    float fr = flo * __builtin_amdgcn_rcpf(flo - fhi);
    fr = fminf(fmaxf(fr, 0.04f), 0.96f);
    int tm = lo + (int)(fr * (float)(hi - lo));
    tm = (tm <= lo) ? (lo + 1) : ((tm >= hi) ? (hi - 1) : tm);

    int c = count_ge(tm);
    bool ge = (c >= 50);
    if (!done){
      if (ge){ fhi = (side==1)  ? fhi*0.5f : fhi; flo = (float)(c-50); lo = tm; side = 1; }
      else   { flo = (side==-1) ? flo*0.5f : flo; fhi = (float)(c-50); hi = tm; side = -1; }
    }
    done = done || (c == 50) || ((hi - lo) <= 1);
  }
  const int thr = lo;

  // ---- final weighted sum: x = key/15360; u32 g = 28*quad+2j+i holds m=2g,2g+1;
  //      ew float2 at ewl + 56*quad + 4j + 2i ----
  float num = 0.f, den = 0.f;
  #pragma unroll
  for (int j=0;j<14;++j){
    #pragma unroll
    for (int i=0;i<2;++i){
      float2 e = *(const float2*)(ewl + 56*quad + 4*j + 2*i);
      int a0 = (kk[j][i]<<16)>>16, a1 = kk[j][i]>>16;
      if (a0 >= thr){ num = fmaf((float)a0, e.x, num); den += e.x; }
      if (a1 >= thr){ num = fmaf((float)a1, e.y, num); den += e.y; }
    }
  }
  num = qsum4_f(num);
  den = qsum4_f(den);

  int cn = cn0 + 16*wv + l16;
  if (quad == 0 && cn < 51000){
    int c = cn/51;
    atomicAdd(bias + (size_t)b*1000 + c, vbuf[cn]*(num/(den*KSC)));
  }
}

// ---------- K7: out = fp32( exp(logit_scale) * bias ) ----------
__global__ void k_out(const float* __restrict__ bias, const float* __restrict__ ls, float* __restrict__ out){
  int i = blockIdx.x*256 + threadIdx.x;
  if (i < 32000){
    float sc = expf(ls[0]);
    out[i] = sc * bias[i];
  }
}

// ---------- launch ----------
extern "C" void kernel_launch(void* const* d_in, const int* in_sizes, int n_in,
                              void* d_out, int out_size, void* d_ws, size_t ws_size,
                              hipStream_t stream) {
  const float* img = (const float*)d_in[0];
  const float* loc = (const float*)d_in[1];
  const float* txt = (const float*)d_in[2];
  const float* ls  = (const float*)d_in[3];
  char* ws = (char*)d_ws;
  float* imgn = (float*)(ws + 0);            //  65536
  float* MT   = (float*)(ws + 65536);        //  2048000
  float* invn = (float*)(ws + 2113536);      //  204032
  float* vbuf = (float*)(ws + 2317568);      //  204032
  float* ewg  = (float*)(ws + 2521600);      //  28672
  float* bias = (float*)(ws + 2550272);      //  128000
  u16*   TXT  = (u16*)  (ws + 2678272);      //  52232192
  u16*   LOC  = (u16*)  (ws + 54910464);     //  7340032

  k_img <<<dim3(32),      dim3(64),  0, stream>>>(img, imgn);
  k_txt <<<dim3(51008),   dim3(64),  0, stream>>>(txt, TXT, invn);
  k_mean<<<dim3(1000),    dim3(256), 0, stream>>>(txt, invn, MT);
  k_v   <<<dim3(1000),    dim3(64),  0, stream>>>(TXT, MT, vbuf);
  k_base<<<dim3(1000),    dim3(64),  0, stream>>>(imgn, MT, bias);
  k_loc <<<dim3(224,32),  dim3(64),  0, stream>>>(loc, imgn, LOC, ewg);
  k_main<<<dim3(25504),   dim3(256), 0, stream>>>(TXT, LOC, ewg, vbuf, bias);
  k_out <<<dim3(125),     dim3(256), 0, stream>>>(bias, ls, (float*)d_out);
}